// Round 6
// baseline (570.913 us; speedup 1.0000x reference)
//
#include <hip/hip_runtime.h>
#include <math.h>

#define TT   8192
#define HH   768
#define FF   3072
#define NEXP 8
#define NP   16384          // T*K pairs
#define BM2  256
#define MTP2 72             // padded 256-row tile count (divisible by 8)
#define ESTR (FF*HH)        // per-expert weight stride (elements)

typedef unsigned short u16;
typedef __attribute__((ext_vector_type(8))) short bf16x8;
typedef __attribute__((ext_vector_type(4))) float f32x4;

__device__ __forceinline__ u16 f2b(float f) {
  unsigned u = __float_as_uint(f);
  unsigned r = (u + 0x7FFFu + ((u >> 16) & 1u)) >> 16;   // RNE
  return (u16)r;
}

__device__ __forceinline__ float gelu_exact(float v) {
  return 0.5f * v * (1.0f + erff(v * 0.70710678118654752f));
}

__device__ __forceinline__ void gll16(const void* g, void* l) {
  __builtin_amdgcn_global_load_lds(
      (const __attribute__((address_space(1))) void*)g,
      (__attribute__((address_space(3))) void*)l, 16, 0, 0);
}

// ---------------- routing ----------------
// hdr layout (ints): [0..7] counts, [8..15] cursors, [16..23] offs, [24] total,
// [32..191] tile_e, [192..351] tile_m, [352..16735] ptok, [16736..33119] pwt(f32)

__global__ void route_zero(int* hdr) {
  int i = blockIdx.x * 64 + threadIdx.x;
  if (i < 32) hdr[i] = 0;
}

__global__ void route_count(const int* __restrict__ te, int* __restrict__ hdr) {
  int i = blockIdx.x * 256 + threadIdx.x;
  if (i < NP) atomicAdd(&hdr[te[i]], 1);
}

__global__ void route_plan(int* hdr) {
  if (threadIdx.x == 0 && blockIdx.x == 0) {
    int* counts = hdr;
    int* offs   = hdr + 16;
    int* tile_e = hdr + 32;
    int* tile_m = hdr + 192;
    int run = 0;
    for (int e = 0; e < NEXP; ++e) { offs[e] = run; run += counts[e]; }
    int tt = 0;
    for (int e = 0; e < NEXP; ++e) {
      int nt = (counts[e] + BM2 - 1) >> 8;
      for (int i = 0; i < nt; ++i) { tile_e[tt] = e; tile_m[tt] = i * BM2; ++tt; }
    }
    hdr[24] = tt;
  }
}

__global__ void route_scatter(const int* __restrict__ te, const float* __restrict__ tw,
                              int* __restrict__ hdr) {
  int i = blockIdx.x * 256 + threadIdx.x;
  if (i < NP) {
    int e = te[i];
    int p = atomicAdd(&hdr[8 + e], 1);
    int idx = hdr[16 + e] + p;
    hdr[352 + idx] = i >> 1;                       // token
    ((float*)(hdr + 16736))[idx] = tw[i];          // weight
  }
}

// ---------------- converts ----------------
__global__ void cvt_bf16x4(const float* __restrict__ src, u16* __restrict__ dst, int n4) {
  int i = blockIdx.x * 256 + threadIdx.x;
  if (i < n4) {
    float4 v = ((const float4*)src)[i];
    ushort4 o;
    o.x = f2b(v.x); o.y = f2b(v.y); o.z = f2b(v.z); o.w = f2b(v.w);
    ((ushort4*)dst)[i] = o;
  }
}

// w2 [E][F][H] f32 -> w2t [E][H][F] bf16
__global__ void transpose_w2(const float* __restrict__ w2, u16* __restrict__ w2t) {
  __shared__ u16 t[32][33];
  int e = blockIdx.z;
  int f0 = blockIdx.x * 32, h0 = blockIdx.y * 32;
  int tx = threadIdx.x, ty = threadIdx.y;
  const float* s = w2 + (size_t)e * ESTR;
  u16* d = w2t + (size_t)e * ESTR;
#pragma unroll
  for (int j = 0; j < 4; ++j) {
    int f = f0 + ty + j * 8;
    t[ty + j * 8][tx] = f2b(s[(size_t)f * HH + h0 + tx]);
  }
  __syncthreads();
#pragma unroll
  for (int j = 0; j < 4; ++j) {
    int h = h0 + ty + j * 8;
    d[(size_t)h * FF + f0 + tx] = t[tx][ty + j * 8];
  }
}

__global__ void bias_init(float* __restrict__ out, const float* __restrict__ bias) {
  int i = blockIdx.x * 256 + threadIdx.x;   // over T*H/4
  if (i < TT * HH / 4)
    ((float4*)out)[i] = ((const float4*)bias)[i % (HH / 4)];
}

// ---------------- grouped fused GEMM, 256x256 tile, 8 waves ----------------
// PHASE 1: h[pair] = gelu(Xg @ w1[e].T)      A gathered [*,768], B=w1 [F][768]
// PHASE 2: out[tok] += (Hg @ w2t[e]) * wt    A=h rows [*,3072], B=w2t [H][3072], split-K
// LDS: [256 rows][64 k] bf16 per buffer, chunk-XOR swizzle (chunk ^= row&7)
// applied on the pre-swizzled GLOBAL source (gll_lds dest linear) and on the
// swizzled ds_read address (both-sides involution).
template <int PHASE, int NT, int G, int KS>
__global__ __launch_bounds__(512, 2)
void moe_gemm(const u16* __restrict__ Asrc, const u16* __restrict__ Bsrc,
              u16* __restrict__ Hout, float* __restrict__ Out,
              const int* __restrict__ hdr) {
  constexpr int KEXT = (PHASE == 1) ? HH : (FF / 2);   // K extent per block
  constexpr int AST  = (PHASE == 1) ? HH : FF;         // A row stride
  constexpr int BST  = (PHASE == 1) ? HH : FF;         // B row stride
  constexpr int NK   = KEXT / 64;

  const int nwg = NT * MTP2 * KS;
  const int bid = blockIdx.x;
  const int l   = (bid & 7) * (nwg >> 3) + (bid >> 3);   // XCD-contiguous
  const int mtl = l % G;
  const int nt  = (l / G) % NT;
  const int kg  = (l / (G * NT)) % KS;
  const int sg  = l / (G * NT * KS);
  const int mt  = sg * G + mtl;
  if (mt >= hdr[24]) return;
  const int kbase = kg * KEXT;

  const int e   = hdr[32 + mt];
  const int m0  = hdr[192 + mt];
  const int cnt = hdr[e];
  const int off = hdr[16 + e];
  const int* ptok = hdr + 352;
  const float* pwt = (const float*)(hdr + 16736);

  __shared__ u16 Al[2][16384];   // [256][64]
  __shared__ u16 Bl[2][16384];

  const int tid  = threadIdx.x;
  const int lane = tid & 63;
  const int wave = tid >> 6;
  const int wm = wave >> 2, wn = wave & 3;   // 2 x 4 waves, wave tile 128x64
  const int lr = lane & 15;

  // staging: inst i covers row r=(tid>>3)+64i, source chunk pre-swizzled
  const int kcs = (((tid & 7) ^ ((tid >> 3) & 7)) * 8);   // elems
  const u16* aptr[4];
  const u16* bptr[4];
#pragma unroll
  for (int i = 0; i < 4; ++i) {
    int r = (tid >> 3) + 64 * i;
    if (PHASE == 1) {
      int g = off + m0 + r; g = g < NP ? g : NP - 1;
      aptr[i] = Asrc + (size_t)ptok[g] * AST + kcs;
    } else {
      int gr = off + m0 + r; gr = gr < NP ? gr : NP - 1;
      aptr[i] = Asrc + (size_t)gr * AST + kbase + kcs;
    }
    int br = nt * 256 + r;
    bptr[i] = Bsrc + (size_t)e * ESTR + (size_t)br * BST + kbase + kcs;
  }

#define STAGE(buf, kk) do {                                  \
    _Pragma("unroll")                                        \
    for (int i = 0; i < 4; ++i) {                            \
      gll16(aptr[i] + (kk), &Al[buf][tid * 8 + i * 4096]);   \
      gll16(bptr[i] + (kk), &Bl[buf][tid * 8 + i * 4096]);   \
    }                                                        \
  } while (0)

  f32x4 acc[8][4] = {};

#define COMPUTE(buf) do {                                                     \
    _Pragma("unroll")                                                         \
    for (int kh = 0; kh < 2; ++kh) {                                          \
      bf16x8 af[8], bfr[4];                                                   \
      _Pragma("unroll")                                                       \
      for (int mi = 0; mi < 8; ++mi) {                                        \
        int rr = wm * 128 + mi * 16 + lr;                                     \
        int pc = (kh * 4 + (lane >> 4)) ^ (rr & 7);                           \
        af[mi] = *(const bf16x8*)&Al[buf][rr * 64 + pc * 8];                  \
      }                                                                       \
      _Pragma("unroll")                                                       \
      for (int ni = 0; ni < 4; ++ni) {                                        \
        int rr = wn * 64 + ni * 16 + lr;                                      \
        int pc = (kh * 4 + (lane >> 4)) ^ (rr & 7);                           \
        bfr[ni] = *(const bf16x8*)&Bl[buf][rr * 64 + pc * 8];                 \
      }                                                                       \
      _Pragma("unroll")                                                       \
      for (int mi = 0; mi < 8; ++mi)                                          \
        _Pragma("unroll")                                                     \
        for (int ni = 0; ni < 4; ++ni)                                        \
          acc[mi][ni] = __builtin_amdgcn_mfma_f32_16x16x32_bf16(              \
              af[mi], bfr[ni], acc[mi][ni], 0, 0, 0);                         \
    }                                                                         \
  } while (0)

  STAGE(0, 0);
  STAGE(1, 64);

  for (int t = 0; t < NK - 1; ++t) {
    const int buf = t & 1;
    asm volatile("s_waitcnt vmcnt(8)" ::: "memory");   // tile t landed
    __builtin_amdgcn_sched_barrier(0);
    __builtin_amdgcn_s_barrier();
    __builtin_amdgcn_sched_barrier(0);
    COMPUTE(buf);
    asm volatile("s_waitcnt lgkmcnt(0)" ::: "memory");
    __builtin_amdgcn_sched_barrier(0);
    __builtin_amdgcn_s_barrier();
    if (t + 2 < NK) STAGE(buf, (t + 2) * 64);
  }
  {
    asm volatile("s_waitcnt vmcnt(0)" ::: "memory");
    __builtin_amdgcn_sched_barrier(0);
    __builtin_amdgcn_s_barrier();
    __builtin_amdgcn_sched_barrier(0);
    COMPUTE((NK - 1) & 1);
  }
#undef STAGE
#undef COMPUTE

  if (PHASE == 1) {
#pragma unroll
    for (int mi = 0; mi < 8; ++mi)
#pragma unroll
      for (int ni = 0; ni < 4; ++ni)
#pragma unroll
        for (int j = 0; j < 4; ++j) {
          int rl = wm * 128 + mi * 16 + (lane >> 4) * 4 + j;
          int gr = m0 + rl;
          if (gr < cnt) {
            int col = nt * 256 + wn * 64 + ni * 16 + lr;
            Hout[(size_t)(off + gr) * FF + col] = f2b(gelu_exact(acc[mi][ni][j]));
          }
        }
  } else {
#pragma unroll
    for (int mi = 0; mi < 8; ++mi)
#pragma unroll
      for (int ni = 0; ni < 4; ++ni)
#pragma unroll
        for (int j = 0; j < 4; ++j) {
          int rl = wm * 128 + mi * 16 + (lane >> 4) * 4 + j;
          int gr = m0 + rl;
          if (gr < cnt) {
            int g = off + gr;
            int col = nt * 256 + wn * 64 + ni * 16 + lr;
            atomicAdd(&Out[(size_t)ptok[g] * HH + col], acc[mi][ni][j] * pwt[g]);
          }
        }
  }
}

// ---------------- naive fallback (ws too small) ----------------
__global__ void naive_pair(const float* __restrict__ x, const float* __restrict__ tw,
                           const int* __restrict__ te, const float* __restrict__ w1,
                           const float* __restrict__ w2, float* __restrict__ out) {
  __shared__ float xs[HH];
  __shared__ float hb[FF];
  int t = blockIdx.x >> 1, k = blockIdx.x & 1;
  int e = te[t * 2 + k];
  float wt = tw[t * 2 + k];
  for (int i = threadIdx.x; i < HH; i += 256) xs[i] = x[(size_t)t * HH + i];
  __syncthreads();
  const float* W1 = w1 + (size_t)e * ESTR;
  for (int f = threadIdx.x; f < FF; f += 256) {
    float s = 0.f;
    const float* r = W1 + (size_t)f * HH;
    for (int i = 0; i < HH; ++i) s += xs[i] * r[i];
    hb[f] = gelu_exact(s);
  }
  __syncthreads();
  const float* W2 = w2 + (size_t)e * ESTR;
  for (int c = threadIdx.x; c < HH; c += 256) {
    float s = 0.f;
    for (int f = 0; f < FF; ++f) s += hb[f] * W2[(size_t)f * HH + c];
    atomicAdd(&out[(size_t)t * HH + c], s * wt);
  }
}

extern "C" void kernel_launch(void* const* d_in, const int* in_sizes, int n_in,
                              void* d_out, int out_size, void* d_ws, size_t ws_size,
                              hipStream_t stream) {
  const float* x    = (const float*)d_in[0];
  // d_in[1] ("weights") is unused by the reference computation
  const float* topw = (const float*)d_in[2];
  const int*   tope = (const int*)d_in[3];
  const float* w1   = (const float*)d_in[4];
  const float* w2   = (const float*)d_in[5];
  const float* bias = (const float*)d_in[6];
  float* out = (float*)d_out;

  char* ws = (char*)d_ws;
  const size_t HDRB   = 1u << 18;                       // 256 KB header
  const size_t xb_off  = HDRB;
  const size_t xb_sz   = (size_t)TT * HH * 2;
  const size_t w1_off  = xb_off + xb_sz;
  const size_t w1_sz   = (size_t)NEXP * ESTR * 2;
  const size_t w2t_off = w1_off + w1_sz;
  const size_t w2t_sz  = w1_sz;
  const size_t h_off   = w2t_off + w2t_sz;
  const size_t h_sz    = (size_t)NP * FF * 2;           // compact: by pair index
  const size_t need    = h_off + h_sz;

  if (ws_size < need) {
    bias_init<<<(TT * HH / 4 + 255) / 256, 256, 0, stream>>>(out, bias);
    naive_pair<<<NP, 256, 0, stream>>>(x, topw, tope, w1, w2, out);
    return;
  }

  int* hdr  = (int*)ws;
  u16* xb   = (u16*)(ws + xb_off);
  u16* w1b  = (u16*)(ws + w1_off);
  u16* w2t  = (u16*)(ws + w2t_off);
  u16* h    = (u16*)(ws + h_off);

  route_zero<<<1, 64, 0, stream>>>(hdr);
  route_count<<<NP / 256, 256, 0, stream>>>(tope, hdr);
  route_plan<<<1, 1, 0, stream>>>(hdr);
  route_scatter<<<NP / 256, 256, 0, stream>>>(tope, topw, hdr);

  cvt_bf16x4<<<TT * HH / 4 / 256, 256, 0, stream>>>(x, xb, TT * HH / 4);
  cvt_bf16x4<<<NEXP * ESTR / 4 / 256, 256, 0, stream>>>(w1, w1b, NEXP * ESTR / 4);
  transpose_w2<<<dim3(FF / 32, HH / 32, NEXP), dim3(32, 8), 0, stream>>>(w2, w2t);
  bias_init<<<(TT * HH / 4 + 255) / 256, 256, 0, stream>>>(out, bias);

  // phase 1: M grouped (256-tiles), N=3072 (NT=12), K=768, G=4, no K-split
  moe_gemm<1, 12, 4, 1><<<12 * MTP2, 512, 0, stream>>>(xb, w1b, h, nullptr, hdr);
  // phase 2: N=768 (NT=3), K=3072 split 2x1536, G=2
  moe_gemm<2, 3, 2, 2><<<3 * MTP2 * 2, 512, 0, stream>>>(h, w2t, nullptr, out, hdr);
}

// Round 8
// 521.394 us; speedup vs baseline: 1.0950x; 1.0950x over previous
//
#include <hip/hip_runtime.h>
#include <math.h>

#define TT   8192
#define HH   768
#define FF   3072
#define NEXP 8
#define NP   16384          // T*K pairs
#define BM   128
#define MAXT 135            // ceil(NP/BM) + NEXP - 1
#define MTP  136            // padded tile count (divisible by 8)
#define ESTR (FF*HH)        // per-expert weight stride (elements)

typedef unsigned short u16;
typedef __attribute__((ext_vector_type(8))) short bf16x8;
typedef __attribute__((ext_vector_type(4))) float f32x4;

__device__ __forceinline__ u16 f2b(float f) {
  unsigned u = __float_as_uint(f);
  unsigned r = (u + 0x7FFFu + ((u >> 16) & 1u)) >> 16;   // RNE
  return (u16)r;
}

__device__ __forceinline__ float gelu_exact(float v) {
  return 0.5f * v * (1.0f + erff(v * 0.70710678118654752f));
}

__device__ __forceinline__ void gll16(const void* g, void* l) {
  __builtin_amdgcn_global_load_lds(
      (const __attribute__((address_space(1))) void*)g,
      (__attribute__((address_space(3))) void*)l, 16, 0, 0);
}

// ---------------- routing ----------------
__global__ void route_zero(int* hdr) {
  int i = blockIdx.x * 64 + threadIdx.x;
  if (i < 32) hdr[i] = 0;
}

__global__ void route_count(const int* __restrict__ te, int* __restrict__ hdr) {
  int i = blockIdx.x * 256 + threadIdx.x;
  if (i < NP) atomicAdd(&hdr[te[i]], 1);
}

__global__ void route_plan(int* hdr) {
  if (threadIdx.x == 0 && blockIdx.x == 0) {
    int* counts = hdr;
    int* offs   = hdr + 16;
    int* tile_e = hdr + 32;
    int* tile_m = hdr + 192;
    int run = 0;
    for (int e = 0; e < NEXP; ++e) { offs[e] = run; run += counts[e]; }
    int tt = 0;
    for (int e = 0; e < NEXP; ++e) {
      int nt = (counts[e] + BM - 1) >> 7;
      for (int i = 0; i < nt; ++i) { tile_e[tt] = e; tile_m[tt] = i * BM; ++tt; }
    }
    hdr[24] = tt;
  }
}

__global__ void route_scatter(const int* __restrict__ te, const float* __restrict__ tw,
                              int* __restrict__ hdr) {
  int i = blockIdx.x * 256 + threadIdx.x;
  if (i < NP) {
    int e = te[i];
    int p = atomicAdd(&hdr[8 + e], 1);
    int idx = hdr[16 + e] + p;
    hdr[352 + idx] = i >> 1;                       // token
    ((float*)(hdr + 16736))[idx] = tw[i];          // weight
  }
}

// ---------------- converts ----------------
__global__ void cvt_bf16x4(const float* __restrict__ src, u16* __restrict__ dst, int n4) {
  int i = blockIdx.x * 256 + threadIdx.x;
  if (i < n4) {
    float4 v = ((const float4*)src)[i];
    ushort4 o;
    o.x = f2b(v.x); o.y = f2b(v.y); o.z = f2b(v.z); o.w = f2b(v.w);
    ((ushort4*)dst)[i] = o;
  }
}

// w2 [E][F][H] f32 -> w2t [E][H][F] bf16
__global__ void transpose_w2(const float* __restrict__ w2, u16* __restrict__ w2t) {
  __shared__ u16 t[32][33];
  int e = blockIdx.z;
  int f0 = blockIdx.x * 32, h0 = blockIdx.y * 32;
  int tx = threadIdx.x, ty = threadIdx.y;
  const float* s = w2 + (size_t)e * ESTR;
  u16* d = w2t + (size_t)e * ESTR;
#pragma unroll
  for (int j = 0; j < 4; ++j) {
    int f = f0 + ty + j * 8;
    t[ty + j * 8][tx] = f2b(s[(size_t)f * HH + h0 + tx]);
  }
  __syncthreads();
#pragma unroll
  for (int j = 0; j < 4; ++j) {
    int h = h0 + ty + j * 8;
    d[(size_t)h * FF + f0 + tx] = t[tx][ty + j * 8];
  }
}

__global__ void bias_init(float* __restrict__ out, const float* __restrict__ bias) {
  int i = blockIdx.x * 256 + threadIdx.x;   // over T*H/4
  if (i < TT * HH / 4)
    ((float4*)out)[i] = ((const float4*)bias)[i % (HH / 4)];
}

// ---------------- grouped fused GEMM, 128x128 tile, 4 waves ----------------
// PHASE 1: h[pair] = gelu(Xg @ w1[e].T)   A gathered [*,768], B=w1 [F][768]
// PHASE 2: out[tok] += (Hg @ w2t[e])*wt   A=h [*,3072], B=w2t [H][3072], split-K
// 3-buffer LDS rotation (tile t -> buf t%3), 3-deep in-flight staging:
//   iter t: vmcnt(4)[tile t landed; t+1,t+2 in flight] -> barrier ->
//           ds_read 8 frags | STAGE(tile t+2 -> buf (t+2)%3) ->
//           lgkmcnt(0) -> 16 MFMA.
// LDS [128][32] linear per buffer; chunk swizzle phys = logical ^ ((row>>1)&3)
// applied on global source col (write side) and ds_read (read side).
template <int PHASE, int NT, int G, int KS>
__global__ __launch_bounds__(256, 3)
void moe_gemm(const u16* __restrict__ Asrc, const u16* __restrict__ Bsrc,
              u16* __restrict__ Hout, float* __restrict__ Out,
              const int* __restrict__ hdr) {
  constexpr int KEXT = (PHASE == 1) ? HH : (FF / KS);
  constexpr int AST  = (PHASE == 1) ? HH : FF;
  constexpr int BST  = (PHASE == 1) ? HH : FF;
  constexpr int NK   = KEXT / 32;           // 24 or 48 (multiple of 3)

  const int nwg = NT * MTP * KS;
  const int bid = blockIdx.x;
  const int l   = (bid & 7) * (nwg >> 3) + (bid >> 3);   // XCD-contiguous
  const int mtl = l % G;
  const int nt  = (l / G) % NT;
  const int kg  = (l / (G * NT)) % KS;
  const int sg  = l / (G * NT * KS);
  const int mt  = sg * G + mtl;
  if (mt >= hdr[24]) return;
  const int kbase = kg * KEXT;

  const int e   = hdr[32 + mt];
  const int m0  = hdr[192 + mt];
  const int cnt = hdr[e];
  const int off = hdr[16 + e];
  const int* ptok = hdr + 352;
  const float* pwt = (const float*)(hdr + 16736);

  __shared__ u16 Al[3][4096];   // [128 rows][32 k] linear
  __shared__ u16 Bl[3][4096];

  const int tid  = threadIdx.x;
  const int lane = tid & 63;
  const int wave = tid >> 6;
  const int wm = wave >> 1, wn = wave & 1;   // 2x2 waves, wave tile 64x64
  const int lr = lane & 15;

  // stage: inst i covers row r=(tid>>2)+64i, phys chunk p=tid&3,
  // source logical chunk = p ^ ((r>>1)&3) = (tid&3) ^ ((tid>>3)&3)
  const int kcs = (((tid & 3) ^ ((tid >> 3) & 3)) * 8);
  const u16* aptr[2];
  const u16* bptr[2];
#pragma unroll
  for (int i = 0; i < 2; ++i) {
    int r = (tid >> 2) + 64 * i;
    if (PHASE == 1) {
      int g = off + m0 + r; g = g < NP ? g : NP - 1;
      aptr[i] = Asrc + (size_t)ptok[g] * AST + kcs;
    } else {
      int gr = off + m0 + r; gr = gr < NP ? gr : NP - 1;
      aptr[i] = Asrc + (size_t)gr * AST + kbase + kcs;
    }
    int br = nt * BM + r;
    bptr[i] = Bsrc + (size_t)e * ESTR + (size_t)br * BST + kbase + kcs;
  }

  f32x4 acc[4][4] = {};
  // read: logical chunk lh=lane>>4 at row rr -> phys = lh ^ ((rr>>1)&3)
  const int pcs = (((lane >> 4) ^ ((lane >> 1) & 3)) * 8);

#define STG(BS, T) do {                              \
    gll16(aptr[0] + (T) * 32, &Al[BS][tid * 8]);     \
    gll16(aptr[1] + (T) * 32, &Al[BS][tid * 8 + 2048]); \
    gll16(bptr[0] + (T) * 32, &Bl[BS][tid * 8]);     \
    gll16(bptr[1] + (T) * 32, &Bl[BS][tid * 8 + 2048]); \
  } while (0)

// one K-tile: wait own tile landed -> barrier -> reads | stage -> mfma
#define ITER(BC, BS, TSTG, DOST, VMN) do {                                   \
    asm volatile("s_waitcnt vmcnt(" #VMN ")" ::: "memory");                  \
    __builtin_amdgcn_sched_barrier(0);                                       \
    __builtin_amdgcn_s_barrier();                                            \
    bf16x8 af[4], bfr[4];                                                    \
    _Pragma("unroll")                                                        \
    for (int i = 0; i < 4; ++i)                                              \
      af[i] = *(const bf16x8*)&Al[BC][(wm * 64 + i * 16 + lr) * 32 + pcs];   \
    _Pragma("unroll")                                                        \
    for (int i = 0; i < 4; ++i)                                              \
      bfr[i] = *(const bf16x8*)&Bl[BC][(wn * 64 + i * 16 + lr) * 32 + pcs];  \
    if (DOST) STG(BS, TSTG);                                                 \
    asm volatile("s_waitcnt lgkmcnt(0)" ::: "memory");                       \
    __builtin_amdgcn_sched_barrier(0);                                       \
    __builtin_amdgcn_s_setprio(1);                                           \
    _Pragma("unroll")                                                        \
    for (int mi = 0; mi < 4; ++mi)                                           \
      _Pragma("unroll")                                                      \
      for (int ni = 0; ni < 4; ++ni)                                         \
        acc[mi][ni] = __builtin_amdgcn_mfma_f32_16x16x32_bf16(               \
            af[mi], bfr[ni], acc[mi][ni], 0, 0, 0);                          \
    __builtin_amdgcn_s_setprio(0);                                           \
  } while (0)

  // prologue: tiles 0,1 into bufs 0,1 (8 loads in flight)
  STG(0, 0);
  STG(1, 1);

  for (int g = 0; g < NK / 3 - 1; ++g) {
    const int t0 = g * 3;
    ITER(0, 2, t0 + 2, 1, 4);
    ITER(1, 0, t0 + 3, 1, 4);
    ITER(2, 1, t0 + 4, 1, 4);
  }
  // final group: tiles NK-3, NK-2, NK-1 (bufs 0,1,2)
  ITER(0, 2, NK - 1, 1, 4);   // stages last tile into buf 2
  ITER(1, 0, 0, 0, 4);
  ITER(2, 0, 0, 0, 0);
#undef ITER
#undef STG

  if (PHASE == 1) {
#pragma unroll
    for (int mi = 0; mi < 4; ++mi)
#pragma unroll
      for (int ni = 0; ni < 4; ++ni)
#pragma unroll
        for (int j = 0; j < 4; ++j) {
          int rl = wm * 64 + mi * 16 + (lane >> 4) * 4 + j;
          int gr = m0 + rl;
          if (gr < cnt) {
            int col = nt * BM + wn * 64 + ni * 16 + lr;
            Hout[(size_t)(off + gr) * FF + col] = f2b(gelu_exact(acc[mi][ni][j]));
          }
        }
  } else {
#pragma unroll
    for (int mi = 0; mi < 4; ++mi)
#pragma unroll
      for (int ni = 0; ni < 4; ++ni)
#pragma unroll
        for (int j = 0; j < 4; ++j) {
          int rl = wm * 64 + mi * 16 + (lane >> 4) * 4 + j;
          int gr = m0 + rl;
          if (gr < cnt) {
            int g = off + gr;
            int col = nt * BM + wn * 64 + ni * 16 + lr;
            atomicAdd(&Out[(size_t)ptok[g] * HH + col], acc[mi][ni][j] * pwt[g]);
          }
        }
  }
}

// ---------------- naive fallback (ws too small) ----------------
__global__ void naive_pair(const float* __restrict__ x, const float* __restrict__ tw,
                           const int* __restrict__ te, const float* __restrict__ w1,
                           const float* __restrict__ w2, float* __restrict__ out) {
  __shared__ float xs[HH];
  __shared__ float hb[FF];
  int t = blockIdx.x >> 1, k = blockIdx.x & 1;
  int e = te[t * 2 + k];
  float wt = tw[t * 2 + k];
  for (int i = threadIdx.x; i < HH; i += 256) xs[i] = x[(size_t)t * HH + i];
  __syncthreads();
  const float* W1 = w1 + (size_t)e * ESTR;
  for (int f = threadIdx.x; f < FF; f += 256) {
    float s = 0.f;
    const float* r = W1 + (size_t)f * HH;
    for (int i = 0; i < HH; ++i) s += xs[i] * r[i];
    hb[f] = gelu_exact(s);
  }
  __syncthreads();
  const float* W2 = w2 + (size_t)e * ESTR;
  for (int c = threadIdx.x; c < HH; c += 256) {
    float s = 0.f;
    for (int f = 0; f < FF; ++f) s += hb[f] * W2[(size_t)f * HH + c];
    atomicAdd(&out[(size_t)t * HH + c], s * wt);
  }
}

extern "C" void kernel_launch(void* const* d_in, const int* in_sizes, int n_in,
                              void* d_out, int out_size, void* d_ws, size_t ws_size,
                              hipStream_t stream) {
  const float* x    = (const float*)d_in[0];
  const float* topw = (const float*)d_in[2];
  const int*   tope = (const int*)d_in[3];
  const float* w1   = (const float*)d_in[4];
  const float* w2   = (const float*)d_in[5];
  const float* bias = (const float*)d_in[6];
  float* out = (float*)d_out;

  char* ws = (char*)d_ws;
  const size_t HDRB   = 1u << 18;                       // 256 KB header
  const size_t xb_off  = HDRB;
  const size_t xb_sz   = (size_t)TT * HH * 2;
  const size_t w1_off  = xb_off + xb_sz;
  const size_t w1_sz   = (size_t)NEXP * ESTR * 2;
  const size_t w2t_off = w1_off + w1_sz;
  const size_t w2t_sz  = w1_sz;
  const size_t h_off   = w2t_off + w2t_sz;
  const size_t h_sz    = (size_t)NP * FF * 2;           // compact: by pair index
  const size_t need    = h_off + h_sz;

  if (ws_size < need) {
    bias_init<<<(TT * HH / 4 + 255) / 256, 256, 0, stream>>>(out, bias);
    naive_pair<<<NP, 256, 0, stream>>>(x, topw, tope, w1, w2, out);
    return;
  }

  int* hdr  = (int*)ws;
  u16* xb   = (u16*)(ws + xb_off);
  u16* w1b  = (u16*)(ws + w1_off);
  u16* w2t  = (u16*)(ws + w2t_off);
  u16* h    = (u16*)(ws + h_off);

  route_zero<<<1, 64, 0, stream>>>(hdr);
  route_count<<<NP / 256, 256, 0, stream>>>(tope, hdr);
  route_plan<<<1, 1, 0, stream>>>(hdr);
  route_scatter<<<NP / 256, 256, 0, stream>>>(tope, topw, hdr);

  cvt_bf16x4<<<TT * HH / 4 / 256, 256, 0, stream>>>(x, xb, TT * HH / 4);
  cvt_bf16x4<<<NEXP * ESTR / 4 / 256, 256, 0, stream>>>(w1, w1b, NEXP * ESTR / 4);
  transpose_w2<<<dim3(FF / 32, HH / 32, NEXP), dim3(32, 8), 0, stream>>>(w2, w2t);
  bias_init<<<(TT * HH / 4 + 255) / 256, 256, 0, stream>>>(out, bias);

  // phase 1: NT=24, G=8, no K-split
  moe_gemm<1, 24, 8, 1><<<24 * MTP, 256, 0, stream>>>(xb, w1b, h, nullptr, hdr);
  // phase 2: NT=6, K=3072 split 2x1536, G=4
  moe_gemm<2, 6, 4, 2><<<6 * MTP * 2, 256, 0, stream>>>(h, w2t, nullptr, out, hdr);
}

// Round 9
// 470.589 us; speedup vs baseline: 1.2132x; 1.1080x over previous
//
#include <hip/hip_runtime.h>
#include <math.h>

#define TT   8192
#define HH   768
#define FF   3072
#define NEXP 8
#define NP   16384          // T*K pairs
#define BM   128
#define MAXT 135            // ceil(NP/BM) + NEXP - 1
#define MTP  136            // padded tile count (divisible by 8)
#define ESTR (FF*HH)        // per-expert weight stride (elements)

typedef unsigned short u16;
typedef __attribute__((ext_vector_type(8))) short bf16x8;
typedef __attribute__((ext_vector_type(4))) float f32x4;

__device__ __forceinline__ u16 f2b(float f) {
  unsigned u = __float_as_uint(f);
  unsigned r = (u + 0x7FFFu + ((u >> 16) & 1u)) >> 16;   // RNE
  return (u16)r;
}

__device__ __forceinline__ float gelu_exact(float v) {
  return 0.5f * v * (1.0f + erff(v * 0.70710678118654752f));
}

__device__ __forceinline__ void gll16(const void* g, void* l) {
  __builtin_amdgcn_global_load_lds(
      (const __attribute__((address_space(1))) void*)g,
      (__attribute__((address_space(3))) void*)l, 16, 0, 0);
}

// ---------------- routing ----------------
// hdr ints: [0..7] counts, [8..15] cursors, [16..23] offs, [24] total,
// [32..191] tile_e, [192..351] tile_m, [352..16735] ptok,
// [16736..33119] pwt(f32), [33120..49503] inv (pair i -> slot)

__global__ void route_count(const int* __restrict__ te, int* __restrict__ hdr) {
  int i = blockIdx.x * 256 + threadIdx.x;
  if (i < NP) atomicAdd(&hdr[te[i]], 1);
}

__global__ void route_plan(int* hdr) {
  if (threadIdx.x == 0 && blockIdx.x == 0) {
    int* counts = hdr;
    int* offs   = hdr + 16;
    int* tile_e = hdr + 32;
    int* tile_m = hdr + 192;
    int run = 0;
    for (int e = 0; e < NEXP; ++e) { offs[e] = run; run += counts[e]; }
    int tt = 0;
    for (int e = 0; e < NEXP; ++e) {
      int nt = (counts[e] + BM - 1) >> 7;
      for (int i = 0; i < nt; ++i) { tile_e[tt] = e; tile_m[tt] = i * BM; ++tt; }
    }
    hdr[24] = tt;
  }
}

__global__ void route_scatter(const int* __restrict__ te, const float* __restrict__ tw,
                              int* __restrict__ hdr) {
  int i = blockIdx.x * 256 + threadIdx.x;
  if (i < NP) {
    int e = te[i];
    int p = atomicAdd(&hdr[8 + e], 1);
    int idx = hdr[16 + e] + p;
    hdr[352 + idx] = i >> 1;                       // token
    ((float*)(hdr + 16736))[idx] = tw[i];          // weight
    hdr[33120 + i] = idx;                          // inverse map
  }
}

// ---------------- converts ----------------
__global__ void cvt_bf16x4(const float* __restrict__ src, u16* __restrict__ dst, int n4) {
  int i = blockIdx.x * 256 + threadIdx.x;
  if (i < n4) {
    float4 v = ((const float4*)src)[i];
    ushort4 o;
    o.x = f2b(v.x); o.y = f2b(v.y); o.z = f2b(v.z); o.w = f2b(v.w);
    ((ushort4*)dst)[i] = o;
  }
}

// w2 [E][F][H] f32 -> w2t [E][H][F] bf16
__global__ void transpose_w2(const float* __restrict__ w2, u16* __restrict__ w2t) {
  __shared__ u16 t[32][33];
  int e = blockIdx.z;
  int f0 = blockIdx.x * 32, h0 = blockIdx.y * 32;
  int tx = threadIdx.x, ty = threadIdx.y;
  const float* s = w2 + (size_t)e * ESTR;
  u16* d = w2t + (size_t)e * ESTR;
#pragma unroll
  for (int j = 0; j < 4; ++j) {
    int f = f0 + ty + j * 8;
    t[ty + j * 8][tx] = f2b(s[(size_t)f * HH + h0 + tx]);
  }
  __syncthreads();
#pragma unroll
  for (int j = 0; j < 4; ++j) {
    int h = h0 + ty + j * 8;
    d[(size_t)h * FF + f0 + tx] = t[tx][ty + j * 8];
  }
}

__global__ void bias_init(float* __restrict__ out, const float* __restrict__ bias) {
  int i = blockIdx.x * 256 + threadIdx.x;   // over T*H/4
  if (i < TT * HH / 4)
    ((float4*)out)[i] = ((const float4*)bias)[i % (HH / 4)];
}

// ---------------- combine: out[t] = bias + tw0*part[inv0] + tw1*part[inv1] ----
__global__ void combine(const float* __restrict__ part, const int* __restrict__ hdr,
                        const float* __restrict__ bias, float* __restrict__ out) {
  int t = blockIdx.x;
  int c = threadIdx.x;                    // 192 threads, float4 each
  const int* inv = hdr + 33120;
  const float* pw = (const float*)(hdr + 16736);
  int g0 = inv[2 * t], g1 = inv[2 * t + 1];
  float w0 = pw[g0], w1 = pw[g1];
  float4 p0 = ((const float4*)(part + (size_t)g0 * HH))[c];
  float4 p1 = ((const float4*)(part + (size_t)g1 * HH))[c];
  float4 b  = ((const float4*)bias)[c];
  float4 o;
  o.x = b.x + w0 * p0.x + w1 * p1.x;
  o.y = b.y + w0 * p0.y + w1 * p1.y;
  o.z = b.z + w0 * p0.z + w1 * p1.z;
  o.w = b.w + w0 * p0.w + w1 * p1.w;
  ((float4*)(out + (size_t)t * HH))[c] = o;
}

// ---------------- grouped fused GEMM, 128x128 tile, 4 waves ----------------
// PHASE 1: h[pair] = gelu(Xg @ w1[e].T)   A gathered [*,768], B=w1 [F][768]
// PHASE 2: part[pair] = Hg @ w2t[e]       A=h [*,3072], B=w2t [H][3072], plain stores
// 3-buffer LDS rotation, 3-deep in-flight staging (vmcnt(4) per iter).
template <int PHASE, int NT, int G, int KS>
__global__ __launch_bounds__(256, 3)
void moe_gemm(const u16* __restrict__ Asrc, const u16* __restrict__ Bsrc,
              u16* __restrict__ Hout, float* __restrict__ Out,
              const int* __restrict__ hdr) {
  constexpr int KEXT = (PHASE == 1) ? HH : (FF / KS);
  constexpr int AST  = (PHASE == 1) ? HH : FF;
  constexpr int BST  = (PHASE == 1) ? HH : FF;
  constexpr int NK   = KEXT / 32;           // 24 or 96 (multiple of 3)

  const int nwg = NT * MTP * KS;
  const int bid = blockIdx.x;
  const int l   = (bid & 7) * (nwg >> 3) + (bid >> 3);   // XCD-contiguous
  const int mtl = l % G;
  const int nt  = (l / G) % NT;
  const int kg  = (l / (G * NT)) % KS;
  const int sg  = l / (G * NT * KS);
  const int mt  = sg * G + mtl;
  if (mt >= hdr[24]) return;
  const int kbase = kg * KEXT;

  const int e   = hdr[32 + mt];
  const int m0  = hdr[192 + mt];
  const int cnt = hdr[e];
  const int off = hdr[16 + e];
  const int* ptok = hdr + 352;

  __shared__ u16 Al[3][4096];   // [128 rows][32 k]
  __shared__ u16 Bl[3][4096];

  const int tid  = threadIdx.x;
  const int lane = tid & 63;
  const int wave = tid >> 6;
  const int wm = wave >> 1, wn = wave & 1;   // 2x2 waves, wave tile 64x64
  const int lr = lane & 15;

  // stage: inst i covers row r=(tid>>2)+64i, phys chunk p=tid&3,
  // source logical chunk = p ^ ((r>>1)&3) = (tid&3) ^ ((tid>>3)&3)
  const int kcs = (((tid & 3) ^ ((tid >> 3) & 3)) * 8);
  const u16* aptr[2];
  const u16* bptr[2];
#pragma unroll
  for (int i = 0; i < 2; ++i) {
    int r = (tid >> 2) + 64 * i;
    if (PHASE == 1) {
      int g = off + m0 + r; g = g < NP ? g : NP - 1;
      aptr[i] = Asrc + (size_t)ptok[g] * AST + kcs;
    } else {
      int gr = off + m0 + r; gr = gr < NP ? gr : NP - 1;
      aptr[i] = Asrc + (size_t)gr * AST + kbase + kcs;
    }
    int br = nt * BM + r;
    bptr[i] = Bsrc + (size_t)e * ESTR + (size_t)br * BST + kbase + kcs;
  }

  f32x4 acc[4][4] = {};
  // read: logical chunk lh=lane>>4 at row rr -> phys = lh ^ ((rr>>1)&3)
  const int pcs = (((lane >> 4) ^ ((lane >> 1) & 3)) * 8);

#define STG(BS, T) do {                              \
    gll16(aptr[0] + (T) * 32, &Al[BS][tid * 8]);     \
    gll16(aptr[1] + (T) * 32, &Al[BS][tid * 8 + 2048]); \
    gll16(bptr[0] + (T) * 32, &Bl[BS][tid * 8]);     \
    gll16(bptr[1] + (T) * 32, &Bl[BS][tid * 8 + 2048]); \
  } while (0)

#define ITER(BC, BS, TSTG, DOST, VMN) do {                                   \
    asm volatile("s_waitcnt vmcnt(" #VMN ")" ::: "memory");                  \
    __builtin_amdgcn_sched_barrier(0);                                       \
    __builtin_amdgcn_s_barrier();                                            \
    bf16x8 af[4], bfr[4];                                                    \
    _Pragma("unroll")                                                        \
    for (int i = 0; i < 4; ++i)                                              \
      af[i] = *(const bf16x8*)&Al[BC][(wm * 64 + i * 16 + lr) * 32 + pcs];   \
    _Pragma("unroll")                                                        \
    for (int i = 0; i < 4; ++i)                                              \
      bfr[i] = *(const bf16x8*)&Bl[BC][(wn * 64 + i * 16 + lr) * 32 + pcs];  \
    if (DOST) STG(BS, TSTG);                                                 \
    asm volatile("s_waitcnt lgkmcnt(0)" ::: "memory");                       \
    __builtin_amdgcn_sched_barrier(0);                                       \
    __builtin_amdgcn_s_setprio(1);                                           \
    _Pragma("unroll")                                                        \
    for (int mi = 0; mi < 4; ++mi)                                           \
      _Pragma("unroll")                                                      \
      for (int ni = 0; ni < 4; ++ni)                                         \
        acc[mi][ni] = __builtin_amdgcn_mfma_f32_16x16x32_bf16(               \
            af[mi], bfr[ni], acc[mi][ni], 0, 0, 0);                          \
    __builtin_amdgcn_s_setprio(0);                                           \
  } while (0)

  STG(0, 0);
  STG(1, 1);

  for (int g = 0; g < NK / 3 - 1; ++g) {
    const int t0 = g * 3;
    ITER(0, 2, t0 + 2, 1, 4);
    ITER(1, 0, t0 + 3, 1, 4);
    ITER(2, 1, t0 + 4, 1, 4);
  }
  ITER(0, 2, NK - 1, 1, 4);
  ITER(1, 0, 0, 0, 4);
  ITER(2, 0, 0, 0, 0);
#undef ITER
#undef STG

  if (PHASE == 1) {
#pragma unroll
    for (int mi = 0; mi < 4; ++mi)
#pragma unroll
      for (int ni = 0; ni < 4; ++ni)
#pragma unroll
        for (int j = 0; j < 4; ++j) {
          int rl = wm * 64 + mi * 16 + (lane >> 4) * 4 + j;
          int gr = m0 + rl;
          if (gr < cnt) {
            int col = nt * BM + wn * 64 + ni * 16 + lr;
            Hout[(size_t)(off + gr) * FF + col] = f2b(gelu_exact(acc[mi][ni][j]));
          }
        }
  } else {
#pragma unroll
    for (int mi = 0; mi < 4; ++mi)
#pragma unroll
      for (int ni = 0; ni < 4; ++ni)
#pragma unroll
        for (int j = 0; j < 4; ++j) {
          int rl = wm * 64 + mi * 16 + (lane >> 4) * 4 + j;
          int gr = m0 + rl;
          if (gr < cnt) {
            int col = nt * BM + wn * 64 + ni * 16 + lr;
            Out[(size_t)(off + gr) * HH + col] = acc[mi][ni][j];   // raw partial
          }
        }
  }
}

// ---------------- naive fallback (ws too small) ----------------
__global__ void naive_pair(const float* __restrict__ x, const float* __restrict__ tw,
                           const int* __restrict__ te, const float* __restrict__ w1,
                           const float* __restrict__ w2, float* __restrict__ out) {
  __shared__ float xs[HH];
  __shared__ float hb[FF];
  int t = blockIdx.x >> 1, k = blockIdx.x & 1;
  int e = te[t * 2 + k];
  float wt = tw[t * 2 + k];
  for (int i = threadIdx.x; i < HH; i += 256) xs[i] = x[(size_t)t * HH + i];
  __syncthreads();
  const float* W1 = w1 + (size_t)e * ESTR;
  for (int f = threadIdx.x; f < FF; f += 256) {
    float s = 0.f;
    const float* r = W1 + (size_t)f * HH;
    for (int i = 0; i < HH; ++i) s += xs[i] * r[i];
    hb[f] = gelu_exact(s);
  }
  __syncthreads();
  const float* W2 = w2 + (size_t)e * ESTR;
  for (int c = threadIdx.x; c < HH; c += 256) {
    float s = 0.f;
    for (int f = 0; f < FF; ++f) s += hb[f] * W2[(size_t)f * HH + c];
    atomicAdd(&out[(size_t)t * HH + c], s * wt);
  }
}

extern "C" void kernel_launch(void* const* d_in, const int* in_sizes, int n_in,
                              void* d_out, int out_size, void* d_ws, size_t ws_size,
                              hipStream_t stream) {
  const float* x    = (const float*)d_in[0];
  const float* topw = (const float*)d_in[2];
  const int*   tope = (const int*)d_in[3];
  const float* w1   = (const float*)d_in[4];
  const float* w2   = (const float*)d_in[5];
  const float* bias = (const float*)d_in[6];
  float* out = (float*)d_out;

  char* ws = (char*)d_ws;
  const size_t HDRB   = 1u << 18;                       // 256 KB header
  const size_t xb_off  = HDRB;
  const size_t xb_sz   = (size_t)TT * HH * 2;
  const size_t w1_off  = xb_off + xb_sz;
  const size_t w1_sz   = (size_t)NEXP * ESTR * 2;
  const size_t w2t_off = w1_off + w1_sz;
  const size_t w2t_sz  = w1_sz;
  const size_t h_off   = w2t_off + w2t_sz;
  const size_t h_sz    = (size_t)NP * FF * 2;           // compact, by pair slot
  const size_t need    = h_off + h_sz;
  // part (NP*HH*4 = 50.3 MB) reuses the xb+w1b region (dead after phase 1;
  // ends at 50.6 MB < w2t_off 63.2 MB).

  if (ws_size < need) {
    bias_init<<<(TT * HH / 4 + 255) / 256, 256, 0, stream>>>(out, bias);
    naive_pair<<<NP, 256, 0, stream>>>(x, topw, tope, w1, w2, out);
    return;
  }

  int* hdr   = (int*)ws;
  u16* xb    = (u16*)(ws + xb_off);
  u16* w1b   = (u16*)(ws + w1_off);
  u16* w2t   = (u16*)(ws + w2t_off);
  u16* h     = (u16*)(ws + h_off);
  float* part = (float*)(ws + xb_off);                  // aliases xb/w1b

  hipMemsetAsync(hdr, 0, 128, stream);
  route_count<<<NP / 256, 256, 0, stream>>>(tope, hdr);
  route_plan<<<1, 1, 0, stream>>>(hdr);
  route_scatter<<<NP / 256, 256, 0, stream>>>(tope, topw, hdr);

  cvt_bf16x4<<<TT * HH / 4 / 256, 256, 0, stream>>>(x, xb, TT * HH / 4);
  cvt_bf16x4<<<NEXP * ESTR / 4 / 256, 256, 0, stream>>>(w1, w1b, NEXP * ESTR / 4);
  transpose_w2<<<dim3(FF / 32, HH / 32, NEXP), dim3(32, 8), 0, stream>>>(w2, w2t);

  // phase 1: NT=24, G=8
  moe_gemm<1, 24, 8, 1><<<24 * MTP, 256, 0, stream>>>(xb, w1b, h, nullptr, hdr);
  // phase 2: NT=6, K=3072, no split, plain stores into part
  moe_gemm<2, 6, 4, 1><<<6 * MTP, 256, 0, stream>>>(h, w2t, nullptr, part, hdr);
  // combine: out = bias + tw0*part[inv0] + tw1*part[inv1]
  combine<<<TT, HH / 4, 0, stream>>>(part, hdr, bias, out);
}

// Round 10
// 356.107 us; speedup vs baseline: 1.6032x; 1.3215x over previous
//
#include <hip/hip_runtime.h>
#include <math.h>

#define TT   8192
#define HH   768
#define FF   3072
#define NEXP 8
#define NP   16384          // T*K pairs
#define BM   128
#define MAXT 135            // ceil(NP/BM) + NEXP - 1
#define MTP  136            // padded tile count (divisible by 8)
#define ESTR (FF*HH)        // per-expert weight stride (elements)

typedef unsigned short u16;
typedef __attribute__((ext_vector_type(8))) short bf16x8;
typedef __attribute__((ext_vector_type(4))) float f32x4;

__device__ __forceinline__ u16 f2b(float f) {
  unsigned u = __float_as_uint(f);
  unsigned r = (u + 0x7FFFu + ((u >> 16) & 1u)) >> 16;   // RNE
  return (u16)r;
}

__device__ __forceinline__ float gelu_exact(float v) {
  return 0.5f * v * (1.0f + erff(v * 0.70710678118654752f));
}

__device__ __forceinline__ void gll16(const void* g, void* l) {
  __builtin_amdgcn_global_load_lds(
      (const __attribute__((address_space(1))) void*)g,
      (__attribute__((address_space(3))) void*)l, 16, 0, 0);
}

// ---------------- routing (single block) ----------------
// hdr ints: [0..7] counts, [16..23] offs, [24] total, [32..191] tile_e,
// [192..351] tile_m, [352..16735] ptok, [16736..33119] pwt(f32),
// [33120..49503] inv (pair i -> slot)
__global__ __launch_bounds__(1024)
void route_all(const int* __restrict__ te, const float* __restrict__ tw,
               int* __restrict__ hdr) {
  __shared__ int cnt[NEXP], offs[NEXP], cur[NEXP];
  const int tid = threadIdx.x;
  const int lane = tid & 63, wave = tid >> 6;
  if (tid < NEXP) cnt[tid] = 0;
  __syncthreads();
  // ballot count: one LDS atomic per wave-chunk per expert
  for (int base = wave * 64; base < NP; base += 1024) {
    int e = te[base + lane];
#pragma unroll
    for (int x = 0; x < NEXP; ++x) {
      unsigned long long m = __ballot(e == x);
      if (lane == 0 && m) atomicAdd(&cnt[x], __popcll(m));
    }
  }
  __syncthreads();
  if (tid == 0) {
    int run = 0, tt = 0;
#pragma unroll
    for (int x = 0; x < NEXP; ++x) {
      offs[x] = run; cur[x] = run;
      hdr[x] = cnt[x]; hdr[16 + x] = run;
      run += cnt[x];
    }
    for (int x = 0; x < NEXP; ++x) {
      int nt = (cnt[x] + BM - 1) >> 7;
      for (int i = 0; i < nt; ++i) { hdr[32 + tt] = x; hdr[192 + tt] = i * BM; ++tt; }
    }
    hdr[24] = tt;
  }
  __syncthreads();
  // stable ballot scatter
  for (int base = wave * 64; base < NP; base += 1024) {
    int i = base + lane;
    int e = te[i];
    float w = tw[i];
    int slot = 0;
#pragma unroll
    for (int x = 0; x < NEXP; ++x) {
      unsigned long long m = __ballot(e == x);
      int nb = __popcll(m);
      int below = __popcll(m & ((1ull << lane) - 1ull));
      int b = 0;
      if (lane == 0) b = nb ? atomicAdd(&cur[x], nb) : 0;
      b = __shfl(b, 0);
      if (e == x) slot = b + below;
    }
    hdr[352 + slot] = i >> 1;
    ((float*)(hdr + 16736))[slot] = w;
    hdr[33120 + i] = slot;
  }
}

// ---------------- merged convert (x then w1; dst regions contiguous) ----------
__global__ void cvt_all(const float* __restrict__ x, const float* __restrict__ w1,
                        u16* __restrict__ dst, int xn4, int totn4) {
  for (int i = blockIdx.x * 256 + threadIdx.x; i < totn4; i += gridDim.x * 256) {
    float4 v = (i < xn4) ? ((const float4*)x)[i] : ((const float4*)w1)[i - xn4];
    ushort4 o;
    o.x = f2b(v.x); o.y = f2b(v.y); o.z = f2b(v.z); o.w = f2b(v.w);
    ((ushort4*)dst)[i] = o;
  }
}

// w2 [E][F][H] f32 -> w2t [E][H][F] bf16, 64x64 tiles, float4 loads
__global__ void transpose_w2(const float* __restrict__ w2, u16* __restrict__ w2t) {
  __shared__ u16 t[64][65];
  int e = blockIdx.z;
  int f0 = blockIdx.x * 64, h0 = blockIdx.y * 64;
  int tid = threadIdx.x;            // 256
  int tx = tid & 15, ty = tid >> 4;
  const float* s = w2 + (size_t)e * ESTR;
#pragma unroll
  for (int j = 0; j < 4; ++j) {
    int f = f0 + ty + 16 * j;
    float4 v = *(const float4*)&s[(size_t)f * HH + h0 + tx * 4];
    t[ty + 16 * j][tx * 4 + 0] = f2b(v.x);
    t[ty + 16 * j][tx * 4 + 1] = f2b(v.y);
    t[ty + 16 * j][tx * 4 + 2] = f2b(v.z);
    t[ty + 16 * j][tx * 4 + 3] = f2b(v.w);
  }
  __syncthreads();
  u16* d = w2t + (size_t)e * ESTR;
#pragma unroll
  for (int j = 0; j < 4; ++j) {
    int hr = ty + 16 * j;
    ushort4 o;
    o.x = t[tx * 4 + 0][hr];
    o.y = t[tx * 4 + 1][hr];
    o.z = t[tx * 4 + 2][hr];
    o.w = t[tx * 4 + 3][hr];
    *(ushort4*)&d[(size_t)(h0 + hr) * FF + f0 + tx * 4] = o;
  }
}

__global__ void bias_init(float* __restrict__ out, const float* __restrict__ bias) {
  int i = blockIdx.x * 256 + threadIdx.x;   // over T*H/4
  if (i < TT * HH / 4)
    ((float4*)out)[i] = ((const float4*)bias)[i % (HH / 4)];
}

// ---------------- combine: out[t] = bias + tw0*part[inv0] + tw1*part[inv1] ----
__global__ void combine(const float* __restrict__ part, const int* __restrict__ hdr,
                        const float* __restrict__ bias, float* __restrict__ out) {
  int t = blockIdx.x;
  int c = threadIdx.x;                    // 192 threads, float4 each
  const int* inv = hdr + 33120;
  const float* pw = (const float*)(hdr + 16736);
  int g0 = inv[2 * t], g1 = inv[2 * t + 1];
  float w0 = pw[g0], w1 = pw[g1];
  float4 p0 = ((const float4*)(part + (size_t)g0 * HH))[c];
  float4 p1 = ((const float4*)(part + (size_t)g1 * HH))[c];
  float4 b  = ((const float4*)bias)[c];
  float4 o;
  o.x = b.x + w0 * p0.x + w1 * p1.x;
  o.y = b.y + w0 * p0.y + w1 * p1.y;
  o.z = b.z + w0 * p0.z + w1 * p1.z;
  o.w = b.w + w0 * p0.w + w1 * p1.w;
  ((float4*)(out + (size_t)t * HH))[c] = o;
}

// ---------------- grouped fused GEMM, 128x128 tile, 4 waves ----------------
// PHASE 1: h[pair] = gelu(Xg @ w1[e].T)   A gathered [*,768], B=w1 [F][768]
// PHASE 2: part[pair] = Hg @ w2t[e]       A=h [*,3072], B=w2t [H][3072], plain stores
// 3-buffer LDS rotation, 3-deep in-flight staging (vmcnt(4) per iter).
template <int PHASE, int NT, int G, int KS>
__global__ __launch_bounds__(256, 3)
void moe_gemm(const u16* __restrict__ Asrc, const u16* __restrict__ Bsrc,
              u16* __restrict__ Hout, float* __restrict__ Out,
              const int* __restrict__ hdr) {
  constexpr int KEXT = (PHASE == 1) ? HH : (FF / KS);
  constexpr int AST  = (PHASE == 1) ? HH : FF;
  constexpr int BST  = (PHASE == 1) ? HH : FF;
  constexpr int NK   = KEXT / 32;           // 24 or 96 (multiple of 3)

  const int nwg = NT * MTP * KS;
  const int bid = blockIdx.x;
  const int l   = (bid & 7) * (nwg >> 3) + (bid >> 3);   // XCD-contiguous
  const int mtl = l % G;
  const int nt  = (l / G) % NT;
  const int kg  = (l / (G * NT)) % KS;
  const int sg  = l / (G * NT * KS);
  const int mt  = sg * G + mtl;
  if (mt >= hdr[24]) return;
  const int kbase = kg * KEXT;

  const int e   = hdr[32 + mt];
  const int m0  = hdr[192 + mt];
  const int cnt = hdr[e];
  const int off = hdr[16 + e];
  const int* ptok = hdr + 352;

  __shared__ u16 Al[3][4096];   // [128 rows][32 k]
  __shared__ u16 Bl[3][4096];

  const int tid  = threadIdx.x;
  const int lane = tid & 63;
  const int wave = tid >> 6;
  const int wm = wave >> 1, wn = wave & 1;   // 2x2 waves, wave tile 64x64
  const int lr = lane & 15;

  const int kcs = (((tid & 3) ^ ((tid >> 3) & 3)) * 8);
  const u16* aptr[2];
  const u16* bptr[2];
#pragma unroll
  for (int i = 0; i < 2; ++i) {
    int r = (tid >> 2) + 64 * i;
    if (PHASE == 1) {
      int g = off + m0 + r; g = g < NP ? g : NP - 1;
      aptr[i] = Asrc + (size_t)ptok[g] * AST + kcs;
    } else {
      int gr = off + m0 + r; gr = gr < NP ? gr : NP - 1;
      aptr[i] = Asrc + (size_t)gr * AST + kbase + kcs;
    }
    int br = nt * BM + r;
    bptr[i] = Bsrc + (size_t)e * ESTR + (size_t)br * BST + kbase + kcs;
  }

  f32x4 acc[4][4] = {};
  const int pcs = (((lane >> 4) ^ ((lane >> 1) & 3)) * 8);

#define STG(BS, T) do {                              \
    gll16(aptr[0] + (T) * 32, &Al[BS][tid * 8]);     \
    gll16(aptr[1] + (T) * 32, &Al[BS][tid * 8 + 2048]); \
    gll16(bptr[0] + (T) * 32, &Bl[BS][tid * 8]);     \
    gll16(bptr[1] + (T) * 32, &Bl[BS][tid * 8 + 2048]); \
  } while (0)

#define ITER(BC, BS, TSTG, DOST, VMN) do {                                   \
    asm volatile("s_waitcnt vmcnt(" #VMN ")" ::: "memory");                  \
    __builtin_amdgcn_sched_barrier(0);                                       \
    __builtin_amdgcn_s_barrier();                                            \
    bf16x8 af[4], bfr[4];                                                    \
    _Pragma("unroll")                                                        \
    for (int i = 0; i < 4; ++i)                                              \
      af[i] = *(const bf16x8*)&Al[BC][(wm * 64 + i * 16 + lr) * 32 + pcs];   \
    _Pragma("unroll")                                                        \
    for (int i = 0; i < 4; ++i)                                              \
      bfr[i] = *(const bf16x8*)&Bl[BC][(wn * 64 + i * 16 + lr) * 32 + pcs];  \
    if (DOST) STG(BS, TSTG);                                                 \
    asm volatile("s_waitcnt lgkmcnt(0)" ::: "memory");                       \
    __builtin_amdgcn_sched_barrier(0);                                       \
    __builtin_amdgcn_s_setprio(1);                                           \
    _Pragma("unroll")                                                        \
    for (int mi = 0; mi < 4; ++mi)                                           \
      _Pragma("unroll")                                                      \
      for (int ni = 0; ni < 4; ++ni)                                         \
        acc[mi][ni] = __builtin_amdgcn_mfma_f32_16x16x32_bf16(               \
            af[mi], bfr[ni], acc[mi][ni], 0, 0, 0);                          \
    __builtin_amdgcn_s_setprio(0);                                           \
  } while (0)

  STG(0, 0);
  STG(1, 1);

  for (int g = 0; g < NK / 3 - 1; ++g) {
    const int t0 = g * 3;
    ITER(0, 2, t0 + 2, 1, 4);
    ITER(1, 0, t0 + 3, 1, 4);
    ITER(2, 1, t0 + 4, 1, 4);
  }
  ITER(0, 2, NK - 1, 1, 4);
  ITER(1, 0, 0, 0, 4);
  ITER(2, 0, 0, 0, 0);
#undef ITER
#undef STG

  if (PHASE == 1) {
#pragma unroll
    for (int mi = 0; mi < 4; ++mi)
#pragma unroll
      for (int ni = 0; ni < 4; ++ni)
#pragma unroll
        for (int j = 0; j < 4; ++j) {
          int rl = wm * 64 + mi * 16 + (lane >> 4) * 4 + j;
          int gr = m0 + rl;
          if (gr < cnt) {
            int col = nt * BM + wn * 64 + ni * 16 + lr;
            Hout[(size_t)(off + gr) * FF + col] = f2b(gelu_exact(acc[mi][ni][j]));
          }
        }
  } else {
#pragma unroll
    for (int mi = 0; mi < 4; ++mi)
#pragma unroll
      for (int ni = 0; ni < 4; ++ni)
#pragma unroll
        for (int j = 0; j < 4; ++j) {
          int rl = wm * 64 + mi * 16 + (lane >> 4) * 4 + j;
          int gr = m0 + rl;
          if (gr < cnt) {
            int col = nt * BM + wn * 64 + ni * 16 + lr;
            Out[(size_t)(off + gr) * HH + col] = acc[mi][ni][j];   // raw partial
          }
        }
  }
}

// ---------------- naive fallback (ws too small) ----------------
__global__ void naive_pair(const float* __restrict__ x, const float* __restrict__ tw,
                           const int* __restrict__ te, const float* __restrict__ w1,
                           const float* __restrict__ w2, float* __restrict__ out) {
  __shared__ float xs[HH];
  __shared__ float hb[FF];
  int t = blockIdx.x >> 1, k = blockIdx.x & 1;
  int e = te[t * 2 + k];
  float wt = tw[t * 2 + k];
  for (int i = threadIdx.x; i < HH; i += 256) xs[i] = x[(size_t)t * HH + i];
  __syncthreads();
  const float* W1 = w1 + (size_t)e * ESTR;
  for (int f = threadIdx.x; f < FF; f += 256) {
    float s = 0.f;
    const float* r = W1 + (size_t)f * HH;
    for (int i = 0; i < HH; ++i) s += xs[i] * r[i];
    hb[f] = gelu_exact(s);
  }
  __syncthreads();
  const float* W2 = w2 + (size_t)e * ESTR;
  for (int c = threadIdx.x; c < HH; c += 256) {
    float s = 0.f;
    for (int f = 0; f < FF; ++f) s += hb[f] * W2[(size_t)f * HH + c];
    atomicAdd(&out[(size_t)t * HH + c], s * wt);
  }
}

extern "C" void kernel_launch(void* const* d_in, const int* in_sizes, int n_in,
                              void* d_out, int out_size, void* d_ws, size_t ws_size,
                              hipStream_t stream) {
  const float* x    = (const float*)d_in[0];
  const float* topw = (const float*)d_in[2];
  const int*   tope = (const int*)d_in[3];
  const float* w1   = (const float*)d_in[4];
  const float* w2   = (const float*)d_in[5];
  const float* bias = (const float*)d_in[6];
  float* out = (float*)d_out;

  char* ws = (char*)d_ws;
  const size_t HDRB   = 1u << 18;                       // 256 KB header
  const size_t xb_off  = HDRB;
  const size_t xb_sz   = (size_t)TT * HH * 2;
  const size_t w1_off  = xb_off + xb_sz;
  const size_t w1_sz   = (size_t)NEXP * ESTR * 2;
  const size_t w2t_off = w1_off + w1_sz;
  const size_t w2t_sz  = w1_sz;
  const size_t h_off   = w2t_off + w2t_sz;
  const size_t h_sz    = (size_t)NP * FF * 2;           // compact, by pair slot
  const size_t need    = h_off + h_sz;
  // part (NP*HH*4 = 50.3 MB) reuses the xb+w1b region (dead after phase 1).

  if (ws_size < need) {
    bias_init<<<(TT * HH / 4 + 255) / 256, 256, 0, stream>>>(out, bias);
    naive_pair<<<NP, 256, 0, stream>>>(x, topw, tope, w1, w2, out);
    return;
  }

  int* hdr   = (int*)ws;
  u16* xb    = (u16*)(ws + xb_off);
  u16* w1b   = (u16*)(ws + w1_off);
  u16* w2t   = (u16*)(ws + w2t_off);
  u16* h     = (u16*)(ws + h_off);
  float* part = (float*)(ws + xb_off);                  // aliases xb/w1b

  route_all<<<1, 1024, 0, stream>>>(tope, topw, hdr);

  const int XN4 = TT * HH / 4;
  const int TOTN4 = (TT * HH + NEXP * ESTR) / 4;
  cvt_all<<<2048, 256, 0, stream>>>(x, w1, xb, XN4, TOTN4);
  transpose_w2<<<dim3(FF / 64, HH / 64, NEXP), 256, 0, stream>>>(w2, w2t);

  // phase 1: NT=24, G=8
  moe_gemm<1, 24, 8, 1><<<24 * MTP, 256, 0, stream>>>(xb, w1b, h, nullptr, hdr);
  // phase 2: NT=6, K=3072, plain stores into part
  moe_gemm<2, 6, 4, 1><<<6 * MTP, 256, 0, stream>>>(h, w2t, nullptr, part, hdr);
  // combine: out = bias + tw0*part[inv0] + tw1*part[inv1]
  combine<<<TT, HH / 4, 0, stream>>>(part, hdr, bias, out);
}